// Round 7
// baseline (3883.987 us; speedup 1.0000x reference)
//
#include <hip/hip_runtime.h>
#include <hip/hip_bf16.h>

#define BATCH 64
#define SEQ   2048
#define ISZ   256
#define H     256
#define G4    1024            // 4*H
#define M_TOT (BATCH*SEQ)     // 131072

typedef _Float16 half8  __attribute__((ext_vector_type(8)));
typedef _Float16 half2v __attribute__((ext_vector_type(2)));
typedef float    f32x4  __attribute__((ext_vector_type(4)));

union U32H2 { unsigned int u; half2v h; };
static __device__ __forceinline__ half2v u2h(unsigned int u){ U32H2 x; x.u = u; return x.h; }
union F32I { float f; int i; };

#if __has_builtin(__builtin_amdgcn_fdot2)
#define FDOT2(w,hp,acc) __builtin_amdgcn_fdot2(u2h(w), u2h(hp), (acc), false)
#else
static __device__ __forceinline__ float fdot2_sw(unsigned int w, unsigned int hp, float acc){
  half2v wv = u2h(w), hv = u2h(hp);
  return acc + (float)wv[0]*(float)hv[0] + (float)wv[1]*(float)hv[1];
}
#define FDOT2(w,hp,acc) fdot2_sw((w),(hp),(acc))
#endif

// Pure-VALU cross-lane ops within a quad. DPP quad_perm: full-rate, no LDS
// port, no SGPR-write hazard (round-1 readlane lesson).
static __device__ __forceinline__ float dpp_xor1(float v){
#if __has_builtin(__builtin_amdgcn_update_dpp)
  F32I a; a.f = v;
  F32I r; r.i = __builtin_amdgcn_update_dpp(0, a.i, 0xB1 /*quad_perm(1,0,3,2)*/, 0xF, 0xF, true);
  return r.f;
#else
  return __shfl_xor(v, 1, 64);
#endif
}
static __device__ __forceinline__ float dpp_xor2(float v){
#if __has_builtin(__builtin_amdgcn_update_dpp)
  F32I a; a.f = v;
  F32I r; r.i = __builtin_amdgcn_update_dpp(0, a.i, 0x4E /*quad_perm(2,3,0,1)*/, 0xF, 0xF, true);
  return r.f;
#else
  return __shfl_xor(v, 2, 64);
#endif
}

// ---------------------------------------------------------------------------
// Prep: f16-convert W_ih, fuse biases, pack W_hh for the quad-gate scan.
// Scan thread t (quad qd=t>>2, lane r'=t&3) owns k-quarter r' of the quad's
// 4 rows {qd, 256+qd, 512+qd, 768+qd} (i,f,g,o of h-element qd).
// For j in [0,128): r_=j>>5 selects the gate row, i_=j&31 the pair:
//   Wq[j*1024 + t] = pack_f16(W_hh[256*r_ + (t>>2)][2*((t&3)*32+i_)], ..+1)
// j 0..95 -> scan registers (i,f,g rows); j 96..127 -> scan LDS (o row).
// ---------------------------------------------------------------------------
__global__ __launch_bounds__(256) void prep_kernel(
    const float* __restrict__ Wih, const float* __restrict__ Whh,
    const float* __restrict__ bih, const float* __restrict__ bhh,
    _Float16* __restrict__ Wihf, unsigned int* __restrict__ Wq,
    float* __restrict__ bias) {
  const int idx = blockIdx.x * 256 + threadIdx.x;     // grid covers 262144 exactly
  Wihf[idx] = (_Float16)Wih[idx];
  if (idx < 131072) {
    const int t = idx & 1023, j = idx >> 10;
    const int r_ = j >> 5, i_ = j & 31;
    const int row = 256*r_ + (t >> 2);
    const int k2  = (t & 3)*32 + i_;
    U32H2 p;
    p.h[0] = (_Float16)Whh[row*256 + 2*k2];
    p.h[1] = (_Float16)Whh[row*256 + 2*k2 + 1];
    Wq[idx] = p.u;
  }
  if (idx < 1024) bias[idx] = bih[idx] + bhh[idx];
}

// ---------------------------------------------------------------------------
// Phase 1: x_proj GEMM (unchanged, proven). C = X * Wih^T + bias, f16 MFMA.
// ---------------------------------------------------------------------------
#define BM 128
#define BN 128
#define BK 32
#define LDA 40

__global__ __launch_bounds__(256) void xproj_gemm(
    const float* __restrict__ X, const _Float16* __restrict__ Wihf,
    const float* __restrict__ bias, _Float16* __restrict__ XP) {
  __shared__ _Float16 As[BM*LDA];
  __shared__ _Float16 Bs[BN*LDA];
  const int tid  = threadIdx.x;
  const int m0   = blockIdx.x * BM;
  const int n0   = blockIdx.y * BN;
  const int lane = tid & 63;
  const int w    = tid >> 6;
  const int wm   = w & 1, wn = w >> 1;
  const int row  = tid >> 1, hlf = tid & 1;   // staging map: 2 threads/row

  f32x4 acc[4][4];
  #pragma unroll
  for (int mi = 0; mi < 4; ++mi)
    #pragma unroll
    for (int ni = 0; ni < 4; ++ni)
      acc[mi][ni] = (f32x4){0.f, 0.f, 0.f, 0.f};

  for (int kt = 0; kt < ISZ/BK; ++kt) {
    const int k0 = kt * BK;
    __syncthreads();
    // stage A (fp32 -> f16) : 16 floats per thread
    {
      const float4* pa = (const float4*)(X + (size_t)(m0+row)*ISZ + k0 + hlf*16);
      float4 f0 = pa[0], f1 = pa[1], f2 = pa[2], f3 = pa[3];
      half8 h0, h1;
      h0[0]=(_Float16)f0.x; h0[1]=(_Float16)f0.y; h0[2]=(_Float16)f0.z; h0[3]=(_Float16)f0.w;
      h0[4]=(_Float16)f1.x; h0[5]=(_Float16)f1.y; h0[6]=(_Float16)f1.z; h0[7]=(_Float16)f1.w;
      h1[0]=(_Float16)f2.x; h1[1]=(_Float16)f2.y; h1[2]=(_Float16)f2.z; h1[3]=(_Float16)f2.w;
      h1[4]=(_Float16)f3.x; h1[5]=(_Float16)f3.y; h1[6]=(_Float16)f3.z; h1[7]=(_Float16)f3.w;
      *(half8*)&As[row*LDA + hlf*16]     = h0;
      *(half8*)&As[row*LDA + hlf*16 + 8] = h1;
      // stage B (already f16): 16 halves per thread
      const half8* pb = (const half8*)(Wihf + (size_t)(n0+row)*ISZ + k0 + hlf*16);
      half8 b0 = pb[0], b1 = pb[1];
      *(half8*)&Bs[row*LDA + hlf*16]     = b0;
      *(half8*)&Bs[row*LDA + hlf*16 + 8] = b1;
    }
    __syncthreads();
    const int kch = (lane >> 4) * 8;
    const int rm  = wm*64 + (lane & 15);
    const int rn  = wn*64 + (lane & 15);
    half8 af[4], bf[4];
    #pragma unroll
    for (int i = 0; i < 4; ++i) {
      af[i] = *(const half8*)&As[(rm + i*16)*LDA + kch];
      bf[i] = *(const half8*)&Bs[(rn + i*16)*LDA + kch];
    }
    #pragma unroll
    for (int mi = 0; mi < 4; ++mi)
      #pragma unroll
      for (int ni = 0; ni < 4; ++ni)
        acc[mi][ni] = __builtin_amdgcn_mfma_f32_16x16x32_f16(af[mi], bf[ni], acc[mi][ni], 0, 0, 0);
  }
  // epilogue: C/D layout col=lane&15, row=(lane>>4)*4+r
  const int col = lane & 15, qr = (lane >> 4) * 4;
  #pragma unroll
  for (int ni = 0; ni < 4; ++ni) {
    const int n  = n0 + wn*64 + ni*16 + col;
    const float bs = bias[n];
    #pragma unroll
    for (int mi = 0; mi < 4; ++mi) {
      #pragma unroll
      for (int r = 0; r < 4; ++r) {
        const int m = m0 + wm*64 + mi*16 + qr + r;
        XP[(size_t)m*G4 + n] = (_Float16)(acc[mi][ni][r] + bs);
      }
    }
  }
}

// ---------------------------------------------------------------------------
// Phase 2: persistent per-batch-item scan. 64 WGs x 1024 threads.
//
// QUAD-GATE layout (round 7): quad qd=t>>2 owns the 4 gate rows
// {qd, 256+qd, 512+qd, 768+qd} = (i,f,g,o) of h-element qd; lane r'=t&3
// computes k-quarter r' partials for all 4 rows (same 128 fdot2 + 8 uint4
// h-reads as round 6). After the quad butterfly each lane holds one
// ACTIVATED gate; 3 more DPPs gather (f,g,o) to lane 0 which updates (c,h)
// in-register. This DELETES the act[] LDS exchange, one barrier, and the
// 4-wave serial tail (~500-700 cyc/step where 12/16 waves idled).
// h2 is double-buffered -> single barrier per step is race-free.
//
// amdgpu_waves_per_eu(4,4): min=max=4 -> allocator budgets 128 ARCH VGPRs.
// Rounds 3/5 proved min-only hints leave it at 64 arch + 64 AGPR (spill-to-
// AGPR), costing ~96 v_accvgpr_read per thread per step on the VALU pipe.
// LDS (132KB) already caps residency at one 1024-thread block/CU, so
// max=4 waves/EU gives up nothing.
//
// W: i,f,g rows (96 u32) register-resident; o row (8 uint4) in wlds.
// h2: 4 quarter regions padded 36 u32 apart, x2 buffers. 1 barrier/step.
// ---------------------------------------------------------------------------
__global__ __launch_bounds__(1024)
__attribute__((amdgpu_waves_per_eu(4, 4)))
void lstm_scan(
    const _Float16* __restrict__ XP, const unsigned int* __restrict__ Wq,
    float* __restrict__ out) {
  __shared__ uint4 wlds[8*1024];                  // 131072 B (o-row quads)
  __shared__ __align__(16) unsigned int h2[2*144]; // double-buffered padded h
  const int t = threadIdx.x;
  const int b = blockIdx.x;
  const int qd = t >> 2, r = t & 3;

  unsigned int wreg[96];                          // i,f,g rows x 32 pairs
  #pragma unroll
  for (int j = 0; j < 96; ++j) wreg[j] = Wq[j*1024 + t];
  #pragma unroll
  for (int j = 0; j < 96; ++j) asm volatile("" : "+v"(wreg[j]));  // load-once pin

  #pragma unroll
  for (int c = 0; c < 8; ++c) {                   // o row: pairs 4c..4c+3
    uint4 v;
    v.x = Wq[(96 + 4*c + 0)*1024 + t];
    v.y = Wq[(96 + 4*c + 1)*1024 + t];
    v.z = Wq[(96 + 4*c + 2)*1024 + t];
    v.w = Wq[(96 + 4*c + 3)*1024 + t];
    wlds[c*1024 + t] = v;
  }
  if (t < 2*144) h2[t] = 0u;

  float c_state = 0.f;                            // meaningful in lane r==0 only
  // xp row for thread t: n = 256*r + qd
  const _Float16* xb = XP + (size_t)b*SEQ*G4 + 256*r + qd;
  float xcur = (float)xb[0];
  float* outb = out + (size_t)b*SEQ*H;
  const unsigned int* hq0 = h2 +       r*36;      // quarter base, buffer 0
  const unsigned int* hq1 = h2 + 144 + r*36;      // quarter base, buffer 1
  // h2 write slot for element qd (f16 index within a buffer, padded layout)
  const int wslot = (qd >> 6)*72 + (qd & 63);
  // activation constants: row type is r (0=i,1=f,2=g,3=o); g uses tanh
  const float sc = (r == 2) ? 2.f : 1.f;          // tanh(x)=2*sig(2x)-1
  const float om = (r == 2) ? 1.f : 0.f;

  #pragma unroll 1
  for (int s = 0; s < SEQ; ++s) {
    __syncthreads();                              // h2[cur] writes visible
    const int sn = (s + 1 < SEQ) ? (s + 1) : s;
    const _Float16 xnext = xb[(size_t)sn * G4];   // prefetch, used next iter

    const unsigned int* hb = (s & 1) ? hq1 : hq0;
    float a0 = 0.f, a1 = 0.f, a2 = 0.f, a3 = 0.f; // quarter partials: i,f,g,o rows
    #pragma unroll
    for (int c = 0; c < 8; ++c) {
      const uint4 hq = *(const uint4*)(hb + 4*c); // 4-addr multicast read
      a0 = FDOT2(wreg[ 0 + 4*c + 0], hq.x, a0);
      a0 = FDOT2(wreg[ 0 + 4*c + 1], hq.y, a0);
      a0 = FDOT2(wreg[ 0 + 4*c + 2], hq.z, a0);
      a0 = FDOT2(wreg[ 0 + 4*c + 3], hq.w, a0);
      a1 = FDOT2(wreg[32 + 4*c + 0], hq.x, a1);
      a1 = FDOT2(wreg[32 + 4*c + 1], hq.y, a1);
      a1 = FDOT2(wreg[32 + 4*c + 2], hq.z, a1);
      a1 = FDOT2(wreg[32 + 4*c + 3], hq.w, a1);
      a2 = FDOT2(wreg[64 + 4*c + 0], hq.x, a2);
      a2 = FDOT2(wreg[64 + 4*c + 1], hq.y, a2);
      a2 = FDOT2(wreg[64 + 4*c + 2], hq.z, a2);
      a2 = FDOT2(wreg[64 + 4*c + 3], hq.w, a2);
      const uint4 wv = wlds[c*1024 + t];
      a3 = FDOT2(wv.x, hq.x, a3);
      a3 = FDOT2(wv.y, hq.y, a3);
      a3 = FDOT2(wv.z, hq.z, a3);
      a3 = FDOT2(wv.w, hq.w, a3);
    }
    // quad butterfly: s0..s3 = full dots of rows i,f,g,o (replicated in quad)
    float s0 = a0 + dpp_xor1(a0); s0 += dpp_xor2(s0);
    float s1 = a1 + dpp_xor1(a1); s1 += dpp_xor2(s1);
    float s2 = a2 + dpp_xor1(a2); s2 += dpp_xor2(s2);
    float s3 = a3 + dpp_xor1(a3); s3 += dpp_xor2(s3);
    // lane r takes its own gate row
    const float glo  = (r & 1) ? s1 : s0;
    const float ghi  = (r & 1) ? s3 : s2;
    const float gate = ((r & 2) ? ghi : glo) + xcur;
    // branchless activation: sig for i,f,o; tanh (=2*sig(2x)-1) for g
    const float sg  = 1.f / (1.f + __expf(-sc * gate));
    const float a   = sc * sg - om;               // lane act: [i,f,g,o]
    // gather f,g,o to lane 0 (all lanes execute; only lane 0 meaningful)
    const float fv = dpp_xor1(a);                 // lane0: f
    const float gv = dpp_xor2(a);                 // lane0: g
    const float ov = dpp_xor1(gv);                // lane0: o (xor3)
    c_state = fv * c_state + a * gv;              // lane0: f*c + i*g
    const float th = 2.f / (1.f + __expf(-2.f * c_state)) - 1.f;
    const float h  = ov * th;                     // lane0: o*tanh(c)
    if (r == 0) {
      outb[(size_t)s*H + qd] = h;
      _Float16* h2n = (_Float16*)(h2 + ((s & 1) ? 0 : 144)); // next buffer
      h2n[wslot] = (_Float16)h;
      if (s == SEQ-1) {
        out[(size_t)BATCH*SEQ*H + (size_t)b*H + qd] = h;                      // final h
        out[(size_t)BATCH*SEQ*H + (size_t)BATCH*H + (size_t)b*H + qd] = c_state; // final c
      }
    }
    xcur = (float)xnext;
  }
}

// ---------------------------------------------------------------------------
// ws layout: [ XP f16 256MB | Wihf f16 512KB | Wq u32 512KB | bias f32 4KB ]
// ---------------------------------------------------------------------------
extern "C" void kernel_launch(void* const* d_in, const int* in_sizes, int n_in,
                              void* d_out, int out_size, void* d_ws, size_t ws_size,
                              hipStream_t stream) {
  const float* x   = (const float*)d_in[0];
  const float* Wih = (const float*)d_in[1];
  const float* Whh = (const float*)d_in[2];
  const float* bih = (const float*)d_in[3];
  const float* bhh = (const float*)d_in[4];
  float* out = (float*)d_out;

  char* ws = (char*)d_ws;
  const size_t XP_BYTES = (size_t)M_TOT * G4 * sizeof(_Float16);   // 268435456
  _Float16*     XPp  = (_Float16*)ws;
  _Float16*     Wihf = (_Float16*)(ws + XP_BYTES);
  unsigned int* Wq   = (unsigned int*)(ws + XP_BYTES + 524288);
  float*        bias = (float*)(ws + XP_BYTES + 1048576);

  prep_kernel<<<dim3(1024),            dim3(256),  0, stream>>>(Wih, Whh, bih, bhh, Wihf, Wq, bias);
  xproj_gemm <<<dim3(M_TOT/BM, G4/BN), dim3(256),  0, stream>>>(x, Wihf, bias, XPp);
  lstm_scan  <<<dim3(BATCH),           dim3(1024), 0, stream>>>(XPp, Wq, out);
}